// Round 5
// baseline (133.382 us; speedup 1.0000x reference)
//
#include <hip/hip_runtime.h>
#include <hip/hip_bf16.h>

#define NROWS 8192
#define KDIM  512
#define NT    64                 // 8192/128 tiles per dim
#define NBLK  (NT*(NT+1)/2)      // upper-triangle tile pairs = 2080
#define SCL1  0x7F7F7F7F         // E8M0 scale bytes = 2^0 = 1.0
#define STRIP_BYTES (32 * KDIM)  // 16384 B per 32-row strip

typedef __attribute__((ext_vector_type(16))) float f32x16;
typedef __attribute__((ext_vector_type(4))) int i32x4;
typedef __attribute__((ext_vector_type(8))) int i32x8;

__device__ __forceinline__ i32x8 mk_op(i32x4 lo, i32x4 hi) {
    i32x8 r;
    r[0] = lo[0]; r[1] = lo[1]; r[2] = lo[2]; r[3] = lo[3];
    r[4] = hi[0]; r[5] = hi[1]; r[6] = hi[2]; r[7] = hi[3];
    return r;
}

// z (fp32) -> fp8 e4m3, written DIRECTLY in MFMA-operand order:
//   zb2 addr = strip*16384 + kstep*2048 + seg*512 + (row&31)*16 + (k&15)
// where k = kstep*64 + seg*16 + ... (seg = granule-of-16B within the K=64 step).
// Lane l of a row-wave owns k-bytes [l*8, l*8+8):
//   kstep = l>>3, seg = (l>>1)&3, halfoff = (l&1)*8.
// Also sq[i] = ||z_i||^2 (fp32) and zero acc/cnt.
__global__ __launch_bounds__(256) void prep_kernel(const float* __restrict__ z,
                                                   unsigned char* __restrict__ zb2,
                                                   float* __restrict__ sq,
                                                   float* __restrict__ acc,
                                                   unsigned* __restrict__ cnt) {
    int wave = threadIdx.x >> 6, lane = threadIdx.x & 63;
    int row = blockIdx.x * 4 + wave;
    const float* zr = z + (size_t)row * KDIM + lane * 8;
    float4 v0 = *(const float4*)zr;
    float4 v1 = *(const float4*)(zr + 4);
    float vals[8] = {v0.x, v0.y, v0.z, v0.w, v1.x, v1.y, v1.z, v1.w};
    float s = 0.f;
#pragma unroll
    for (int i = 0; i < 8; ++i) s += vals[i] * vals[i];
    int lo = __builtin_amdgcn_cvt_pk_fp8_f32(vals[0], vals[1], 0, false);
    lo     = __builtin_amdgcn_cvt_pk_fp8_f32(vals[2], vals[3], lo, true);
    int hi = __builtin_amdgcn_cvt_pk_fp8_f32(vals[4], vals[5], 0, false);
    hi     = __builtin_amdgcn_cvt_pk_fp8_f32(vals[6], vals[7], hi, true);
    int2 pk; pk.x = lo; pk.y = hi;
    int strip = row >> 5, lr = row & 31;
    size_t addr = (size_t)strip * STRIP_BYTES + (lane >> 3) * 2048 +
                  ((lane >> 1) & 3) * 512 + lr * 16 + (lane & 1) * 8;
    *(int2*)(zb2 + addr) = pk;
#pragma unroll
    for (int off = 32; off; off >>= 1) s += __shfl_down(s, off);
    if (lane == 0) sq[row] = s;
    if (blockIdx.x == 0 && threadIdx.x == 0) { acc[0] = 0.f; cnt[0] = 0u; }
}

// One 128x128 Gram tile per block. NO LDS, NO barriers in the K-loop:
// fragments stream straight from L2 in operand order via coalesced dwordx4.
__global__ __launch_bounds__(256) void gram_kernel(const unsigned char* __restrict__ zb2,
                                                   const float* __restrict__ sq,
                                                   float* __restrict__ acc,
                                                   unsigned* __restrict__ cnt,
                                                   float* __restrict__ out) {
    __shared__ float wsum[4];

    int tid = threadIdx.x;
    int wave = tid >> 6, lane = tid & 63;
    int ln31 = lane & 31, kh = lane >> 5;
    int wm = wave >> 1, wn = wave & 1;

    // linear block id -> (bi, bj), bi <= bj
    int rem = blockIdx.x, bi = 0;
    while (rem >= NT - bi) { rem -= NT - bi; ++bi; }
    int bj = bi + rem;

    // strips: 4 per 128-row tile; this wave uses 2 A-strips and 2 B-strips
    int sA = bi * 4 + wm * 2;
    int sB = bj * 4 + wn * 2;
    int laneOff = kh * 1024 + ln31 * 16;           // seg=2*kh, +512 for seg=2*kh+1
    const unsigned char* pA0 = zb2 + (size_t)sA * STRIP_BYTES + laneOff;
    const unsigned char* pA1 = pA0 + STRIP_BYTES;
    const unsigned char* pB0 = zb2 + (size_t)sB * STRIP_BYTES + laneOff;
    const unsigned char* pB1 = pB0 + STRIP_BYTES;

    f32x16 accf[2][2];
#pragma unroll
    for (int mi = 0; mi < 2; ++mi)
#pragma unroll
        for (int ni = 0; ni < 2; ++ni)
#pragma unroll
            for (int r = 0; r < 16; ++r) accf[mi][ni][r] = 0.f;

#pragma unroll
    for (int kstep = 0; kstep < 8; ++kstep) {
        int off = kstep * 2048;
        i32x8 a0 = mk_op(*(const i32x4*)(pA0 + off), *(const i32x4*)(pA0 + off + 512));
        i32x8 a1 = mk_op(*(const i32x4*)(pA1 + off), *(const i32x4*)(pA1 + off + 512));
        i32x8 b0 = mk_op(*(const i32x4*)(pB0 + off), *(const i32x4*)(pB0 + off + 512));
        i32x8 b1 = mk_op(*(const i32x4*)(pB1 + off), *(const i32x4*)(pB1 + off + 512));
        accf[0][0] = __builtin_amdgcn_mfma_scale_f32_32x32x64_f8f6f4(a0, b0, accf[0][0], 0, 0, 0, SCL1, 0, SCL1);
        accf[0][1] = __builtin_amdgcn_mfma_scale_f32_32x32x64_f8f6f4(a0, b1, accf[0][1], 0, 0, 0, SCL1, 0, SCL1);
        accf[1][0] = __builtin_amdgcn_mfma_scale_f32_32x32x64_f8f6f4(a1, b0, accf[1][0], 0, 0, 0, SCL1, 0, SCL1);
        accf[1][1] = __builtin_amdgcn_mfma_scale_f32_32x32x64_f8f6f4(a1, b1, accf[1][1], 0, 0, 0, SCL1, 0, SCL1);
    }

    // ---- fused epilogue: exp(-D/tau) for gi<gj ----
    int rowBase = bi * 128 + wm * 64;
    int colBase = bj * 128 + wn * 64;
    float sqj[2] = { sq[colBase + ln31], sq[colBase + 32 + ln31] };

    float local = 0.f;
#pragma unroll
    for (int mi = 0; mi < 2; ++mi) {
#pragma unroll
        for (int reg = 0; reg < 16; ++reg) {
            int rowf = (reg & 3) + 8 * (reg >> 2) + 4 * kh;   // 32x32 C/D row (m74/m101, verified r4)
            int gi = rowBase + mi * 32 + rowf;
            float sqi = sq[gi];
#pragma unroll
            for (int ni = 0; ni < 2; ++ni) {
                int gj = colBase + ni * 32 + ln31;            // C/D col = lane&31
                float d = sqi + sqj[ni] - 2.f * accf[mi][ni][reg];
                d = fmaxf(d, 0.f);
                float e = __expf(d * (-1.f / 100.f));
                local += (gi < gj) ? e : 0.f;
            }
        }
    }

#pragma unroll
    for (int off = 32; off; off >>= 1) local += __shfl_down(local, off);
    if (lane == 0) wsum[wave] = local;
    __syncthreads();
    if (tid == 0) {
        atomicAdd(acc, wsum[0] + wsum[1] + wsum[2] + wsum[3]);
        __threadfence();
        unsigned t = atomicAdd(cnt, 1u);
        if (t == NBLK - 1) {
            float total = 2.f * atomicAdd(acc, 0.f);
            out[0] = logf(total / ((float)NROWS * (float)(NROWS - 1)));
        }
    }
}

extern "C" void kernel_launch(void* const* d_in, const int* in_sizes, int n_in,
                              void* d_out, int out_size, void* d_ws, size_t ws_size,
                              hipStream_t stream) {
    const float* z = (const float*)d_in[0];
    float* out = (float*)d_out;
    unsigned char* zb2 = (unsigned char*)d_ws;                    // 4 MB fp8, operand order
    float* sq = (float*)((char*)d_ws + (size_t)NROWS * KDIM);     // 32 KB
    float* acc = sq + NROWS;                                      // 4 B
    unsigned* cnt = (unsigned*)(acc + 1);                         // 4 B

    prep_kernel<<<NROWS / 4, 256, 0, stream>>>(z, zb2, sq, acc, cnt);
    gram_kernel<<<NBLK, 256, 0, stream>>>(zb2, sq, acc, cnt, out);
}

// Round 6
// 95.722 us; speedup vs baseline: 1.3934x; 1.3934x over previous
//
#include <hip/hip_runtime.h>
#include <hip/hip_bf16.h>

#define NROWS 8192
#define KDIM  512
#define NT    64                 // 8192/128 tiles per dim
#define NBLK  (NT*(NT+1)/2)      // upper-triangle tile pairs = 2080
#define SCL1  0x7F7F7F7F         // E8M0 scale bytes = 2^0 = 1.0
#define STRIP_BYTES (32 * KDIM)  // 16384 B per 32-row strip

typedef __attribute__((ext_vector_type(16))) float f32x16;
typedef __attribute__((ext_vector_type(4))) int i32x4;
typedef __attribute__((ext_vector_type(8))) int i32x8;

__device__ __forceinline__ i32x8 mk_op(i32x4 lo, i32x4 hi) {
    i32x8 r;
    r[0] = lo[0]; r[1] = lo[1]; r[2] = lo[2]; r[3] = lo[3];
    r[4] = hi[0]; r[5] = hi[1]; r[6] = hi[2]; r[7] = hi[3];
    return r;
}

// z (fp32) -> fp8 e4m3, written DIRECTLY in MFMA-operand order:
//   zb2 addr = strip*16384 + kstep*2048 + seg*512 + (row&31)*16 + (k&15)
// (layout HW-verified in round 4/5: absmax 0.0). Also sq[i] = ||z_i||^2.
__global__ __launch_bounds__(256) void prep_kernel(const float* __restrict__ z,
                                                   unsigned char* __restrict__ zb2,
                                                   float* __restrict__ sq) {
    int wave = threadIdx.x >> 6, lane = threadIdx.x & 63;
    int row = blockIdx.x * 4 + wave;
    const float* zr = z + (size_t)row * KDIM + lane * 8;
    float4 v0 = *(const float4*)zr;
    float4 v1 = *(const float4*)(zr + 4);
    float vals[8] = {v0.x, v0.y, v0.z, v0.w, v1.x, v1.y, v1.z, v1.w};
    float s = 0.f;
#pragma unroll
    for (int i = 0; i < 8; ++i) s += vals[i] * vals[i];
    int lo = __builtin_amdgcn_cvt_pk_fp8_f32(vals[0], vals[1], 0, false);
    lo     = __builtin_amdgcn_cvt_pk_fp8_f32(vals[2], vals[3], lo, true);
    int hi = __builtin_amdgcn_cvt_pk_fp8_f32(vals[4], vals[5], 0, false);
    hi     = __builtin_amdgcn_cvt_pk_fp8_f32(vals[6], vals[7], hi, true);
    int2 pk; pk.x = lo; pk.y = hi;
    int strip = row >> 5, lr = row & 31;
    size_t addr = (size_t)strip * STRIP_BYTES + (lane >> 3) * 2048 +
                  ((lane >> 1) & 3) * 512 + lr * 16 + (lane & 1) * 8;
    *(int2*)(zb2 + addr) = pk;
#pragma unroll
    for (int off = 32; off; off >>= 1) s += __shfl_down(s, off);
    if (lane == 0) sq[row] = s;
}

// One 128x128 Gram tile per block; direct-from-L2 operand streaming with
// explicit next-kstep register prefetch. NO global atomics: one plain store
// of the block partial into part[blockIdx.x].
__global__ __launch_bounds__(256, 2) void gram_kernel(const unsigned char* __restrict__ zb2,
                                                      const float* __restrict__ sq,
                                                      float* __restrict__ part) {
    __shared__ float wsum[4];

    int tid = threadIdx.x;
    int wave = tid >> 6, lane = tid & 63;
    int ln31 = lane & 31, kh = lane >> 5;
    int wm = wave >> 1, wn = wave & 1;

    // linear block id -> (bi, bj), bi <= bj
    int rem = blockIdx.x, bi = 0;
    while (rem >= NT - bi) { rem -= NT - bi; ++bi; }
    int bj = bi + rem;

    int sA = bi * 4 + wm * 2;
    int sB = bj * 4 + wn * 2;
    int laneOff = kh * 1024 + ln31 * 16;
    const unsigned char* pA0 = zb2 + (size_t)sA * STRIP_BYTES + laneOff;
    const unsigned char* pA1 = pA0 + STRIP_BYTES;
    const unsigned char* pB0 = zb2 + (size_t)sB * STRIP_BYTES + laneOff;
    const unsigned char* pB1 = pB0 + STRIP_BYTES;

    f32x16 accf[2][2];
#pragma unroll
    for (int mi = 0; mi < 2; ++mi)
#pragma unroll
        for (int ni = 0; ni < 2; ++ni)
#pragma unroll
            for (int r = 0; r < 16; ++r) accf[mi][ni][r] = 0.f;

    // cur/nxt: [A0lo,A0hi,A1lo,A1hi,B0lo,B0hi,B1lo,B1hi]
    i32x4 cur[8], nxt[8];
    cur[0] = *(const i32x4*)(pA0);       cur[1] = *(const i32x4*)(pA0 + 512);
    cur[2] = *(const i32x4*)(pA1);       cur[3] = *(const i32x4*)(pA1 + 512);
    cur[4] = *(const i32x4*)(pB0);       cur[5] = *(const i32x4*)(pB0 + 512);
    cur[6] = *(const i32x4*)(pB1);       cur[7] = *(const i32x4*)(pB1 + 512);

#pragma unroll
    for (int kstep = 0; kstep < 8; ++kstep) {
        if (kstep < 7) {
            int off = (kstep + 1) * 2048;
            nxt[0] = *(const i32x4*)(pA0 + off);  nxt[1] = *(const i32x4*)(pA0 + off + 512);
            nxt[2] = *(const i32x4*)(pA1 + off);  nxt[3] = *(const i32x4*)(pA1 + off + 512);
            nxt[4] = *(const i32x4*)(pB0 + off);  nxt[5] = *(const i32x4*)(pB0 + off + 512);
            nxt[6] = *(const i32x4*)(pB1 + off);  nxt[7] = *(const i32x4*)(pB1 + off + 512);
        }
        i32x8 a0 = mk_op(cur[0], cur[1]);
        i32x8 a1 = mk_op(cur[2], cur[3]);
        i32x8 b0 = mk_op(cur[4], cur[5]);
        i32x8 b1 = mk_op(cur[6], cur[7]);
        accf[0][0] = __builtin_amdgcn_mfma_scale_f32_32x32x64_f8f6f4(a0, b0, accf[0][0], 0, 0, 0, SCL1, 0, SCL1);
        accf[0][1] = __builtin_amdgcn_mfma_scale_f32_32x32x64_f8f6f4(a0, b1, accf[0][1], 0, 0, 0, SCL1, 0, SCL1);
        accf[1][0] = __builtin_amdgcn_mfma_scale_f32_32x32x64_f8f6f4(a1, b0, accf[1][0], 0, 0, 0, SCL1, 0, SCL1);
        accf[1][1] = __builtin_amdgcn_mfma_scale_f32_32x32x64_f8f6f4(a1, b1, accf[1][1], 0, 0, 0, SCL1, 0, SCL1);
#pragma unroll
        for (int q = 0; q < 8; ++q) cur[q] = nxt[q];
    }

    // ---- fused epilogue: exp(-D/tau) for gi<gj ----
    int rowBase = bi * 128 + wm * 64;
    int colBase = bj * 128 + wn * 64;
    float sqj[2] = { sq[colBase + ln31], sq[colBase + 32 + ln31] };

    float local = 0.f;
#pragma unroll
    for (int mi = 0; mi < 2; ++mi) {
#pragma unroll
        for (int reg = 0; reg < 16; ++reg) {
            int rowf = (reg & 3) + 8 * (reg >> 2) + 4 * kh;   // 32x32 C/D row (HW-verified)
            int gi = rowBase + mi * 32 + rowf;
            float sqi = sq[gi];
#pragma unroll
            for (int ni = 0; ni < 2; ++ni) {
                int gj = colBase + ni * 32 + ln31;            // C/D col = lane&31
                float d = sqi + sqj[ni] - 2.f * accf[mi][ni][reg];
                d = fmaxf(d, 0.f);
                float e = __expf(d * (-1.f / 100.f));
                local += (gi < gj) ? e : 0.f;
            }
        }
    }

#pragma unroll
    for (int off = 32; off; off >>= 1) local += __shfl_down(local, off);
    if (lane == 0) wsum[wave] = local;
    __syncthreads();
    if (tid == 0) part[blockIdx.x] = wsum[0] + wsum[1] + wsum[2] + wsum[3];  // plain store
}

// Single small block: sum the 2080 partials, take the log.
__global__ __launch_bounds__(256) void reduce_kernel(const float* __restrict__ part,
                                                     float* __restrict__ out) {
    int tid = threadIdx.x;
    int wave = tid >> 6, lane = tid & 63;
    float s = 0.f;
    for (int i = tid; i < NBLK; i += 256) s += part[i];
#pragma unroll
    for (int off = 32; off; off >>= 1) s += __shfl_down(s, off);
    __shared__ float w[4];
    if (lane == 0) w[wave] = s;
    __syncthreads();
    if (tid == 0) {
        float total = 2.f * (w[0] + w[1] + w[2] + w[3]);
        out[0] = logf(total / ((float)NROWS * (float)(NROWS - 1)));
    }
}

extern "C" void kernel_launch(void* const* d_in, const int* in_sizes, int n_in,
                              void* d_out, int out_size, void* d_ws, size_t ws_size,
                              hipStream_t stream) {
    const float* z = (const float*)d_in[0];
    float* out = (float*)d_out;
    unsigned char* zb2 = (unsigned char*)d_ws;                    // 4 MB fp8, operand order
    float* sq = (float*)((char*)d_ws + (size_t)NROWS * KDIM);     // 32 KB
    float* part = sq + NROWS;                                     // 2080 floats

    prep_kernel<<<NROWS / 4, 256, 0, stream>>>(z, zb2, sq);
    gram_kernel<<<NBLK, 256, 0, stream>>>(zb2, sq, part);
    reduce_kernel<<<1, 256, 0, stream>>>(part, out);
}

// Round 7
// 93.883 us; speedup vs baseline: 1.4207x; 1.0196x over previous
//
#include <hip/hip_runtime.h>
#include <hip/hip_bf16.h>

#define NROWS 8192
#define KDIM  512
#define NT    64                 // 8192/128 tiles per dim
#define NBLK  (NT*(NT+1)/2)      // upper-triangle tile pairs = 2080
#define SCL1  0x7F7F7F7F         // E8M0 scale bytes = 2^0 = 1.0
#define STRIP_BYTES (32 * KDIM)  // 16384 B per 32-row strip

typedef __attribute__((ext_vector_type(16))) float f32x16;
typedef __attribute__((ext_vector_type(4))) int i32x4;
typedef __attribute__((ext_vector_type(8))) int i32x8;

__device__ __forceinline__ i32x8 mk_op(i32x4 lo, i32x4 hi) {
    i32x8 r;
    r[0] = lo[0]; r[1] = lo[1]; r[2] = lo[2]; r[3] = lo[3];
    r[4] = hi[0]; r[5] = hi[1]; r[6] = hi[2]; r[7] = hi[3];
    return r;
}

// z (fp32) -> fp8 e4m3, written DIRECTLY in MFMA-operand order:
//   zb2 addr = strip*16384 + kstep*2048 + seg*512 + (row&31)*16 + (k&15)
// (layout HW-verified rounds 4-6: absmax 0.0). Also sq[i] = ||z_i||^2.
__global__ __launch_bounds__(256) void prep_kernel(const float* __restrict__ z,
                                                   unsigned char* __restrict__ zb2,
                                                   float* __restrict__ sq) {
    int wave = threadIdx.x >> 6, lane = threadIdx.x & 63;
    int row = blockIdx.x * 4 + wave;
    const float* zr = z + (size_t)row * KDIM + lane * 8;
    float4 v0 = *(const float4*)zr;
    float4 v1 = *(const float4*)(zr + 4);
    float vals[8] = {v0.x, v0.y, v0.z, v0.w, v1.x, v1.y, v1.z, v1.w};
    float s = 0.f;
#pragma unroll
    for (int i = 0; i < 8; ++i) s += vals[i] * vals[i];
    int lo = __builtin_amdgcn_cvt_pk_fp8_f32(vals[0], vals[1], 0, false);
    lo     = __builtin_amdgcn_cvt_pk_fp8_f32(vals[2], vals[3], lo, true);
    int hi = __builtin_amdgcn_cvt_pk_fp8_f32(vals[4], vals[5], 0, false);
    hi     = __builtin_amdgcn_cvt_pk_fp8_f32(vals[6], vals[7], hi, true);
    int2 pk; pk.x = lo; pk.y = hi;
    int strip = row >> 5, lr = row & 31;
    size_t addr = (size_t)strip * STRIP_BYTES + (lane >> 3) * 2048 +
                  ((lane >> 1) & 3) * 512 + lr * 16 + (lane & 1) * 8;
    *(int2*)(zb2 + addr) = pk;
#pragma unroll
    for (int off = 32; off; off >>= 1) s += __shfl_down(s, off);
    if (lane == 0) sq[row] = s;
}

// One 128x128 Gram tile per block; operands streamed straight from L2 in
// half-K batches: 32 loads in flight (512 B/lane), then 16 MFMA — one
// latency exposure per half-K instead of one per kstep. No LDS staging,
// no barriers, no atomics.
__global__ __launch_bounds__(256, 2) void gram_kernel(const unsigned char* __restrict__ zb2,
                                                      const float* __restrict__ sq,
                                                      float* __restrict__ part) {
    __shared__ float wsum[4];

    int tid = threadIdx.x;
    int wave = tid >> 6, lane = tid & 63;
    int ln31 = lane & 31, kh = lane >> 5;
    int wm = wave >> 1, wn = wave & 1;

    // linear block id -> (bi, bj), bi <= bj
    int rem = blockIdx.x, bi = 0;
    while (rem >= NT - bi) { rem -= NT - bi; ++bi; }
    int bj = bi + rem;

    int sA = bi * 4 + wm * 2;
    int sB = bj * 4 + wn * 2;
    int laneOff = kh * 1024 + ln31 * 16;
    const unsigned char* pA0 = zb2 + (size_t)sA * STRIP_BYTES + laneOff;
    const unsigned char* pA1 = pA0 + STRIP_BYTES;
    const unsigned char* pB0 = zb2 + (size_t)sB * STRIP_BYTES + laneOff;
    const unsigned char* pB1 = pB0 + STRIP_BYTES;

    f32x16 accf[2][2];
#pragma unroll
    for (int mi = 0; mi < 2; ++mi)
#pragma unroll
        for (int ni = 0; ni < 2; ++ni)
#pragma unroll
            for (int r = 0; r < 16; ++r) accf[mi][ni][r] = 0.f;

    // half-K batches: ksteps [4h, 4h+3]
#pragma unroll
    for (int h = 0; h < 2; ++h) {
        i32x4 Av[16], Bv[16];   // [ks][op]: op = {A0lo,A0hi,A1lo,A1hi}
#pragma unroll
        for (int ks = 0; ks < 4; ++ks) {
            int off = (h * 4 + ks) * 2048;
            Av[ks * 4 + 0] = *(const i32x4*)(pA0 + off);
            Av[ks * 4 + 1] = *(const i32x4*)(pA0 + off + 512);
            Av[ks * 4 + 2] = *(const i32x4*)(pA1 + off);
            Av[ks * 4 + 3] = *(const i32x4*)(pA1 + off + 512);
            Bv[ks * 4 + 0] = *(const i32x4*)(pB0 + off);
            Bv[ks * 4 + 1] = *(const i32x4*)(pB0 + off + 512);
            Bv[ks * 4 + 2] = *(const i32x4*)(pB1 + off);
            Bv[ks * 4 + 3] = *(const i32x4*)(pB1 + off + 512);
        }
#pragma unroll
        for (int ks = 0; ks < 4; ++ks) {
            i32x8 a0 = mk_op(Av[ks * 4 + 0], Av[ks * 4 + 1]);
            i32x8 a1 = mk_op(Av[ks * 4 + 2], Av[ks * 4 + 3]);
            i32x8 b0 = mk_op(Bv[ks * 4 + 0], Bv[ks * 4 + 1]);
            i32x8 b1 = mk_op(Bv[ks * 4 + 2], Bv[ks * 4 + 3]);
            accf[0][0] = __builtin_amdgcn_mfma_scale_f32_32x32x64_f8f6f4(a0, b0, accf[0][0], 0, 0, 0, SCL1, 0, SCL1);
            accf[0][1] = __builtin_amdgcn_mfma_scale_f32_32x32x64_f8f6f4(a0, b1, accf[0][1], 0, 0, 0, SCL1, 0, SCL1);
            accf[1][0] = __builtin_amdgcn_mfma_scale_f32_32x32x64_f8f6f4(a1, b0, accf[1][0], 0, 0, 0, SCL1, 0, SCL1);
            accf[1][1] = __builtin_amdgcn_mfma_scale_f32_32x32x64_f8f6f4(a1, b1, accf[1][1], 0, 0, 0, SCL1, 0, SCL1);
        }
    }

    // ---- fused epilogue: exp(-D/tau) for gi<gj ----
    int rowBase = bi * 128 + wm * 64;
    int colBase = bj * 128 + wn * 64;
    float sqj[2] = { sq[colBase + ln31], sq[colBase + 32 + ln31] };

    float local = 0.f;
#pragma unroll
    for (int mi = 0; mi < 2; ++mi) {
#pragma unroll
        for (int reg = 0; reg < 16; ++reg) {
            int rowf = (reg & 3) + 8 * (reg >> 2) + 4 * kh;   // 32x32 C/D row (HW-verified)
            int gi = rowBase + mi * 32 + rowf;
            float sqi = sq[gi];
#pragma unroll
            for (int ni = 0; ni < 2; ++ni) {
                int gj = colBase + ni * 32 + ln31;            // C/D col = lane&31
                float d = sqi + sqj[ni] - 2.f * accf[mi][ni][reg];
                d = fmaxf(d, 0.f);
                float e = __expf(d * (-1.f / 100.f));
                local += (gi < gj) ? e : 0.f;
            }
        }
    }

#pragma unroll
    for (int off = 32; off; off >>= 1) local += __shfl_down(local, off);
    if (lane == 0) wsum[wave] = local;
    __syncthreads();
    if (tid == 0) part[blockIdx.x] = wsum[0] + wsum[1] + wsum[2] + wsum[3];  // plain store
}

// Single small block: sum the 2080 partials, take the log.
__global__ __launch_bounds__(256) void reduce_kernel(const float* __restrict__ part,
                                                     float* __restrict__ out) {
    int tid = threadIdx.x;
    int wave = tid >> 6, lane = tid & 63;
    float s = 0.f;
    for (int i = tid; i < NBLK; i += 256) s += part[i];
#pragma unroll
    for (int off = 32; off; off >>= 1) s += __shfl_down(s, off);
    __shared__ float w[4];
    if (lane == 0) w[wave] = s;
    __syncthreads();
    if (tid == 0) {
        float total = 2.f * (w[0] + w[1] + w[2] + w[3]);
        out[0] = logf(total / ((float)NROWS * (float)(NROWS - 1)));
    }
}

extern "C" void kernel_launch(void* const* d_in, const int* in_sizes, int n_in,
                              void* d_out, int out_size, void* d_ws, size_t ws_size,
                              hipStream_t stream) {
    const float* z = (const float*)d_in[0];
    float* out = (float*)d_out;
    unsigned char* zb2 = (unsigned char*)d_ws;                    // 4 MB fp8, operand order
    float* sq = (float*)((char*)d_ws + (size_t)NROWS * KDIM);     // 32 KB
    float* part = sq + NROWS;                                     // 2080 floats

    prep_kernel<<<NROWS / 4, 256, 0, stream>>>(z, zb2, sq);
    gram_kernel<<<NBLK, 256, 0, stream>>>(zb2, sq, part);
    reduce_kernel<<<1, 256, 0, stream>>>(part, out);
}

// Round 8
// 91.842 us; speedup vs baseline: 1.4523x; 1.0222x over previous
//
#include <hip/hip_runtime.h>
#include <hip/hip_bf16.h>

#define NROWS 8192
#define KDIM  512
#define NT    64                 // 8192/128 tiles per dim
#define NBLK  (NT*(NT+1)/2)      // upper-triangle tile pairs = 2080
#define SCL1  0x7F7F7F7F         // E8M0 scale bytes = 2^0 = 1.0
#define STRIP_BYTES (32 * KDIM)  // 16384 B per 32-row strip
#define C2    0.0144269504f      // log2(e)/100

typedef __attribute__((ext_vector_type(16))) float f32x16;
typedef __attribute__((ext_vector_type(4))) int i32x4;
typedef __attribute__((ext_vector_type(8))) int i32x8;

__device__ __forceinline__ i32x8 mk_op(i32x4 lo, i32x4 hi) {
    i32x8 r;
    r[0] = lo[0]; r[1] = lo[1]; r[2] = lo[2]; r[3] = lo[3];
    r[4] = hi[0]; r[5] = hi[1]; r[6] = hi[2]; r[7] = hi[3];
    return r;
}

// z (fp32) -> fp8 e4m3 in MFMA-operand order (HW-verified rounds 4-7):
//   zb2 addr = strip*16384 + kstep*2048 + seg*512 + (row&31)*16 + (k&15)
// nq[i] = -log2e/100 * ||z_i||^2  (epilogue-ready form).
__global__ __launch_bounds__(256) void prep_kernel(const float* __restrict__ z,
                                                   unsigned char* __restrict__ zb2,
                                                   float* __restrict__ nq) {
    int wave = threadIdx.x >> 6, lane = threadIdx.x & 63;
    int row = blockIdx.x * 4 + wave;
    const float* zr = z + (size_t)row * KDIM + lane * 8;
    float4 v0 = *(const float4*)zr;
    float4 v1 = *(const float4*)(zr + 4);
    float vals[8] = {v0.x, v0.y, v0.z, v0.w, v1.x, v1.y, v1.z, v1.w};
    float s = 0.f;
#pragma unroll
    for (int i = 0; i < 8; ++i) s += vals[i] * vals[i];
    int lo = __builtin_amdgcn_cvt_pk_fp8_f32(vals[0], vals[1], 0, false);
    lo     = __builtin_amdgcn_cvt_pk_fp8_f32(vals[2], vals[3], lo, true);
    int hi = __builtin_amdgcn_cvt_pk_fp8_f32(vals[4], vals[5], 0, false);
    hi     = __builtin_amdgcn_cvt_pk_fp8_f32(vals[6], vals[7], hi, true);
    int2 pk; pk.x = lo; pk.y = hi;
    int strip = row >> 5, lr = row & 31;
    size_t addr = (size_t)strip * STRIP_BYTES + (lane >> 3) * 2048 +
                  ((lane >> 1) & 3) * 512 + lr * 16 + (lane & 1) * 8;
    *(int2*)(zb2 + addr) = pk;
#pragma unroll
    for (int off = 32; off; off >>= 1) s += __shfl_down(s, off);
    if (lane == 0) nq[row] = -C2 * s;
}

// One 128x128 Gram tile per block; operands streamed from L2 in half-K
// batches. K sweep starts at rot=blockIdx&7 so concurrently-resident blocks
// sharing a strip read DIFFERENT k-slices (de-correlates same-line bursts
// at the L2 banks). fp32 MFMA accumulation is order-independent.
__global__ __launch_bounds__(256, 2) void gram_kernel(const unsigned char* __restrict__ zb2,
                                                      const float* __restrict__ nq,
                                                      float* __restrict__ part) {
    __shared__ float wsum[4];

    int tid = threadIdx.x;
    int wave = tid >> 6, lane = tid & 63;
    int ln31 = lane & 31, kh = lane >> 5;
    int wm = wave >> 1, wn = wave & 1;

    // linear block id -> (bi, bj), bi <= bj
    int rem = blockIdx.x, bi = 0;
    while (rem >= NT - bi) { rem -= NT - bi; ++bi; }
    int bj = bi + rem;
    int rot = blockIdx.x & 7;

    int sA = bi * 4 + wm * 2;
    int sB = bj * 4 + wn * 2;
    int laneOff = kh * 1024 + ln31 * 16;
    const unsigned char* pA0 = zb2 + (size_t)sA * STRIP_BYTES + laneOff;
    const unsigned char* pA1 = pA0 + STRIP_BYTES;
    const unsigned char* pB0 = zb2 + (size_t)sB * STRIP_BYTES + laneOff;
    const unsigned char* pB1 = pB0 + STRIP_BYTES;

    f32x16 accf[2][2];
#pragma unroll
    for (int mi = 0; mi < 2; ++mi)
#pragma unroll
        for (int ni = 0; ni < 2; ++ni)
#pragma unroll
            for (int r = 0; r < 16; ++r) accf[mi][ni][r] = 0.f;

#pragma unroll
    for (int h = 0; h < 2; ++h) {
        i32x4 Av[16], Bv[16];
#pragma unroll
        for (int ks = 0; ks < 4; ++ks) {
            int off = (((h * 4 + ks + rot) & 7)) * 2048;   // rotated k-slice
            Av[ks * 4 + 0] = *(const i32x4*)(pA0 + off);
            Av[ks * 4 + 1] = *(const i32x4*)(pA0 + off + 512);
            Av[ks * 4 + 2] = *(const i32x4*)(pA1 + off);
            Av[ks * 4 + 3] = *(const i32x4*)(pA1 + off + 512);
            Bv[ks * 4 + 0] = *(const i32x4*)(pB0 + off);
            Bv[ks * 4 + 1] = *(const i32x4*)(pB0 + off + 512);
            Bv[ks * 4 + 2] = *(const i32x4*)(pB1 + off);
            Bv[ks * 4 + 3] = *(const i32x4*)(pB1 + off + 512);
        }
#pragma unroll
        for (int ks = 0; ks < 4; ++ks) {
            i32x8 a0 = mk_op(Av[ks * 4 + 0], Av[ks * 4 + 1]);
            i32x8 a1 = mk_op(Av[ks * 4 + 2], Av[ks * 4 + 3]);
            i32x8 b0 = mk_op(Bv[ks * 4 + 0], Bv[ks * 4 + 1]);
            i32x8 b1 = mk_op(Bv[ks * 4 + 2], Bv[ks * 4 + 3]);
            accf[0][0] = __builtin_amdgcn_mfma_scale_f32_32x32x64_f8f6f4(a0, b0, accf[0][0], 0, 0, 0, SCL1, 0, SCL1);
            accf[0][1] = __builtin_amdgcn_mfma_scale_f32_32x32x64_f8f6f4(a0, b1, accf[0][1], 0, 0, 0, SCL1, 0, SCL1);
            accf[1][0] = __builtin_amdgcn_mfma_scale_f32_32x32x64_f8f6f4(a1, b0, accf[1][0], 0, 0, 0, SCL1, 0, SCL1);
            accf[1][1] = __builtin_amdgcn_mfma_scale_f32_32x32x64_f8f6f4(a1, b1, accf[1][1], 0, 0, 0, SCL1, 0, SCL1);
        }
    }

    // ---- fused epilogue: exp2( min( s*2C2 + nq_i + nq_j, 0 ) ) ----
    int rowBase = bi * 128 + wm * 64;
    int colBase = bj * 128 + wn * 64;
    float nqj[2] = { nq[colBase + ln31], nq[colBase + 32 + ln31] };

    float local = 0.f;
    if (bi != bj) {
        // off-diagonal tile: gi < gj always — no mask needed
#pragma unroll
        for (int mi = 0; mi < 2; ++mi) {
#pragma unroll
            for (int reg = 0; reg < 16; ++reg) {
                int rowf = (reg & 3) + 8 * (reg >> 2) + 4 * kh;
                float nqi = nq[rowBase + mi * 32 + rowf];
#pragma unroll
                for (int ni = 0; ni < 2; ++ni) {
                    float arg = fmaf(accf[mi][ni][reg], 2.f * C2, nqi + nqj[ni]);
                    local += __builtin_exp2f(fminf(arg, 0.f));
                }
            }
        }
    } else {
#pragma unroll
        for (int mi = 0; mi < 2; ++mi) {
#pragma unroll
            for (int reg = 0; reg < 16; ++reg) {
                int rowf = (reg & 3) + 8 * (reg >> 2) + 4 * kh;
                int gi = rowBase + mi * 32 + rowf;
                float nqi = nq[gi];
#pragma unroll
                for (int ni = 0; ni < 2; ++ni) {
                    int gj = colBase + ni * 32 + ln31;
                    float arg = fmaf(accf[mi][ni][reg], 2.f * C2, nqi + nqj[ni]);
                    float e = __builtin_exp2f(fminf(arg, 0.f));
                    local += (gi < gj) ? e : 0.f;
                }
            }
        }
    }

#pragma unroll
    for (int off = 32; off; off >>= 1) local += __shfl_down(local, off);
    if (lane == 0) wsum[wave] = local;
    __syncthreads();
    if (tid == 0) part[blockIdx.x] = wsum[0] + wsum[1] + wsum[2] + wsum[3];  // plain store
}

// Single small block: sum the 2080 partials, take the log.
__global__ __launch_bounds__(256) void reduce_kernel(const float* __restrict__ part,
                                                     float* __restrict__ out) {
    int tid = threadIdx.x;
    int wave = tid >> 6, lane = tid & 63;
    float s = 0.f;
    for (int i = tid; i < NBLK; i += 256) s += part[i];
#pragma unroll
    for (int off = 32; off; off >>= 1) s += __shfl_down(s, off);
    __shared__ float w[4];
    if (lane == 0) w[wave] = s;
    __syncthreads();
    if (tid == 0) {
        float total = 2.f * (w[0] + w[1] + w[2] + w[3]);
        out[0] = logf(total / ((float)NROWS * (float)(NROWS - 1)));
    }
}

extern "C" void kernel_launch(void* const* d_in, const int* in_sizes, int n_in,
                              void* d_out, int out_size, void* d_ws, size_t ws_size,
                              hipStream_t stream) {
    const float* z = (const float*)d_in[0];
    float* out = (float*)d_out;
    unsigned char* zb2 = (unsigned char*)d_ws;                    // 4 MB fp8, operand order
    float* nq = (float*)((char*)d_ws + (size_t)NROWS * KDIM);     // 32 KB
    float* part = nq + NROWS;                                     // 2080 floats

    prep_kernel<<<NROWS / 4, 256, 0, stream>>>(z, zb2, nq);
    gram_kernel<<<NBLK, 256, 0, stream>>>(zb2, nq, part);
    reduce_kernel<<<1, 256, 0, stream>>>(part, out);
}